// Round 2
// baseline (257.469 us; speedup 1.0000x reference)
//
#include <hip/hip_runtime.h>
#include <math.h>

#define N_NODES 200000
#define NF 128
#define NT 32
#define NS 32
#define NG 128
#define SPLITS 16
#define TILE 64
#define XPAD 132   // x row stride in LDS floats: odd multiple of 16B -> conflict-free b128
#define NHPAD 36   // nh row stride: (4j+t)%32 distinct per lane -> conflict-free b32

__device__ __forceinline__ float rcp_fast(float x) { return __builtin_amdgcn_rcpf(x); }

__global__ __launch_bounds__(256, 2)
void ect_kernel(const float* __restrict__ x,
                const int* __restrict__ batch,   // int32! (JAX demotes int64 without x64)
                const float* __restrict__ v,
                float* __restrict__ out)
{
    __shared__ float v_lds[NT * NF];        // 16384 B
    __shared__ float x_lds[TILE * XPAD];    // 33792 B
    __shared__ float nh_lds[TILE * NHPAD];  //  9216 B   total ~58 KB -> 2 blocks/CU

    const int tid   = threadIdx.x;
    const int g     = blockIdx.x >> 4;
    const int split = blockIdx.x & (SPLITS - 1);

    // load v into LDS (coalesced float4)
    for (int j = tid; j < NT * NF / 4; j += 256) {
        ((float4*)v_lds)[j] = ((const float4*)v)[j];
    }

    // binary search: [g_start, g_end) of this graph in sorted batch (uniform -> broadcast loads)
    int lo = 0, hi = N_NODES;
    while (lo < hi) { int mid = (lo + hi) >> 1; if (batch[mid] < g) lo = mid + 1; else hi = mid; }
    const int g_start = lo;
    hi = N_NODES;
    while (lo < hi) { int mid = (lo + hi) >> 1; if (batch[mid] < g + 1) lo = mid + 1; else hi = mid; }
    const int g_end = lo;

    const int count = g_end - g_start;
    const int chunk = (count + SPLITS - 1) / SPLITS;
    int my_start = g_start + split * chunk;
    if (my_start > g_end) my_start = g_end;
    int my_end = my_start + chunk;
    if (my_end > g_end) my_end = g_end;
    const int my_count = my_end - my_start;

    const float L    = 144.26950408889634f;  // SCALE * log2(e)
    const float dlin = 2.2f / 31.0f;

    // sigmoid-phase ownership: thread -> (t, s = sb + 8k, k=0..3)
    const int t  = tid & 31;
    const int sb = tid >> 5;   // 0..7
    float acc[4] = {0.f, 0.f, 0.f, 0.f};
    float negA[4];
    #pragma unroll
    for (int k = 0; k < 4; ++k) {
        float lin_s = -1.1f + (float)(sb + 8 * k) * dlin;
        negA[k] = -L * lin_s;
    }

    // nh-phase ownership: thread -> (node, t in [w*8, w*8+8))
    const int node = tid & 63;
    const int w    = tid >> 6;

    for (int tile_start = my_start; tile_start < my_end; tile_start += TILE) {
        const int nvalid = min(TILE, my_end - tile_start);
        __syncthreads();   // protect LDS from previous iteration's readers

        // stage x tile (fully coalesced float4 global reads)
        #pragma unroll
        for (int j = 0; j < 8; ++j) {
            int idx4 = j * 256 + tid;      // 0..2047
            int nn   = idx4 >> 5;          // node 0..63
            int f4   = idx4 & 31;
            if (nn < nvalid) {
                float4 val = *(const float4*)&x[(size_t)(tile_start + nn) * NF + f4 * 4];
                *(float4*)&x_lds[nn * XPAD + f4 * 4] = val;
            }
        }
        __syncthreads();

        // nh = x . v^T for this tile
        if (node < nvalid) {
            float nh8[8] = {0.f,0.f,0.f,0.f,0.f,0.f,0.f,0.f};
            for (int f4 = 0; f4 < 32; ++f4) {
                float4 xv = *(const float4*)&x_lds[node * XPAD + f4 * 4];
                #pragma unroll
                for (int tt = 0; tt < 8; ++tt) {
                    float4 vv = *(const float4*)&v_lds[(w * 8 + tt) * NF + f4 * 4];  // wave-uniform -> broadcast
                    nh8[tt] = fmaf(xv.x, vv.x, nh8[tt]);
                    nh8[tt] = fmaf(xv.y, vv.y, nh8[tt]);
                    nh8[tt] = fmaf(xv.z, vv.z, nh8[tt]);
                    nh8[tt] = fmaf(xv.w, vv.w, nh8[tt]);
                }
            }
            *(float4*)&nh_lds[node * NHPAD + w * 8]     = make_float4(nh8[0], nh8[1], nh8[2], nh8[3]);
            *(float4*)&nh_lds[node * NHPAD + w * 8 + 4] = make_float4(nh8[4], nh8[5], nh8[6], nh8[7]);
        }
        __syncthreads();

        // sigmoid accumulate: acc[k] += 1/(1 + exp2(L*h - L*lin_s))
        for (int j = 0; j < nvalid; ++j) {
            float h = nh_lds[j * NHPAD + t];
            #pragma unroll
            for (int k = 0; k < 4; ++k) {
                float e = __builtin_amdgcn_exp2f(fmaf(L, h, negA[k]));
                acc[k] += rcp_fast(1.0f + e);
            }
        }
    }

    // subtract the constant pad term exactly: count * sigmoid(SCALE*(lin_s - R))
    #pragma unroll
    for (int k = 0; k < 4; ++k) {
        int s = sb + 8 * k;
        float lin_s = -1.1f + (float)s * dlin;
        float cs = rcp_fast(1.0f + __builtin_amdgcn_exp2f(L * (1.1f - lin_s)));
        float val = acc[k] - (float)my_count * cs;
        atomicAdd(&out[(size_t)g * (NS * NT) + s * NT + t], val);
    }
}

extern "C" void kernel_launch(void* const* d_in, const int* in_sizes, int n_in,
                              void* d_out, int out_size, void* d_ws, size_t ws_size,
                              hipStream_t stream) {
    const float* x     = (const float*)d_in[0];
    const int*   batch = (const int*)d_in[1];
    const float* v     = (const float*)d_in[3];
    float*       out   = (float*)d_out;

    hipMemsetAsync(d_out, 0, (size_t)out_size * sizeof(float), stream);
    ect_kernel<<<dim3(NG * SPLITS), dim3(256), 0, stream>>>(x, batch, v, out);
}